// Round 5
// baseline (274.139 us; speedup 1.0000x reference)
//
#include <hip/hip_runtime.h>
#include <cfloat>
#include <cstdint>

// KNN classify via split-f16 MFMA emulated-fp32 GEMM.
// key = dot(x,t) - ||t||^2/2 ; dot = hiA*hiB + hiA*loB + loA*hiB (f32-accum MFMA).
// X_train pre-split into tile-packed f16 hi/lo; staged via global_load_lds.
// Norm folded via 2 augment MFMAs (bit-identical to validated r3/r4 sequence).
// Top-5 largest keys, ties -> smaller train index (lax.top_k on -dist semantics).

#define NTRAIN 100000
#define D 128
#define T 1024
#define TB 256          // tests per block (4 waves x 64)
#define NT 32           // trains per tile
#define KNN 5
#define NUM_CLASSES 10
#define NTILE_TOT 3125  // NTRAIN / NT exactly
#define TILE_HALVES 8192   // per packed tile: hi 4096 + lo 4096 halves (16KB)

typedef _Float16 half8 __attribute__((ext_vector_type(8)));
typedef float f32x16 __attribute__((ext_vector_type(16)));

#define MFMA(a, b, c) __builtin_amdgcn_mfma_f32_32x32x16_f16((a), (b), (c), 0, 0, 0)

struct Cand { float s; int j; };

__device__ __forceinline__ bool better(float s, int j, const Cand& c) {
    return (s > c.s) || (s == c.s && j < c.j);
}

__device__ __forceinline__ void ins5(Cand t5[KNN], float s, int j) {
    if (!better(s, j, t5[4])) return;
    if (better(s, j, t5[0]))      { t5[4]=t5[3]; t5[3]=t5[2]; t5[2]=t5[1]; t5[1]=t5[0]; t5[0]={s,j}; }
    else if (better(s, j, t5[1])) { t5[4]=t5[3]; t5[3]=t5[2]; t5[2]=t5[1]; t5[1]={s,j}; }
    else if (better(s, j, t5[2])) { t5[4]=t5[3]; t5[3]=t5[2]; t5[2]={s,j}; }
    else if (better(s, j, t5[3])) { t5[4]=t5[3]; t5[3]={s,j}; }
    else                          { t5[4]={s,j}; }
}

__device__ __forceinline__ float max16(const f32x16& a) {
    float m0 = fmaxf(a[0], a[1]),  m1 = fmaxf(a[2], a[3]);
    float m2 = fmaxf(a[4], a[5]),  m3 = fmaxf(a[6], a[7]);
    float m4 = fmaxf(a[8], a[9]),  m5 = fmaxf(a[10], a[11]);
    float m6 = fmaxf(a[12], a[13]), m7 = fmaxf(a[14], a[15]);
    m0 = fmaxf(m0, m1); m2 = fmaxf(m2, m3); m4 = fmaxf(m4, m5); m6 = fmaxf(m6, m7);
    return fmaxf(fmaxf(m0, m2), fmaxf(m4, m6));
}

__device__ __forceinline__ void gload_lds16(const void* g, void* l) {
    __builtin_amdgcn_global_load_lds(
        (const __attribute__((address_space(1))) uint32_t*)g,
        (__attribute__((address_space(3))) uint32_t*)l, 16, 0, 0);
}

// ---- norms only (fallback path) — tree bit-matches r2/r3 validated kernels ----
__global__ __launch_bounds__(256)
void knn_norms(const float* __restrict__ XT, uint32_t* __restrict__ nrmp) {
    const int j = blockIdx.x * 256 + threadIdx.x;
    if (j >= NTRAIN) return;
    const float4* row = (const float4*)&XT[(size_t)j * D];
    float p[32];
#pragma unroll
    for (int c = 0; c < 32; ++c) {
        float4 v = row[c];
        p[c] = v.x * v.x + v.y * v.y + v.z * v.z + v.w * v.w;
    }
#pragma unroll
    for (int s = 1; s < 32; s <<= 1)
#pragma unroll
        for (int i = 0; i < 32; i += 2 * s) p[i] += p[i + s];
    const float m = -0.5f * p[0];
    const _Float16 mh = (_Float16)m;
    const _Float16 ml = (_Float16)(m - (float)mh);
    union { _Float16 h[2]; uint32_t u; } cv;
    cv.h[0] = mh; cv.h[1] = ml;
    nrmp[j] = cv.u;
}

// ---- fused: pack XT into tile-packed hi/lo f16 + packed norms ----
// Norm tree: thread owns 4 consecutive float4-leaves -> (q0+q1)+(q2+q3), then
// shfl_xor 1,2,4 across the row's 8 threads. Identical pairing tree to
// knn_norms (commutativity only) -> bit-identical results.
__global__ __launch_bounds__(256)
void knn_pack(const float* __restrict__ XT, _Float16* __restrict__ XTs,
              uint32_t* __restrict__ nrmp) {
    __shared__ __align__(16) float sb[32 * D];
    const int tid  = threadIdx.x;
    const int tile = blockIdx.x;
    const float4* src = (const float4*)&XT[(size_t)tile * 32 * D];
#pragma unroll
    for (int p = 0; p < 4; ++p)
        *(float4*)&sb[(p * 256 + tid) * 4] = src[p * 256 + tid];
    __syncthreads();

    {   // pack (conversion ops bit-identical to r4 knn_pack)
        const int ks = tid >> 5, kh = (tid >> 4) & 1, rp = (tid & 15) * 2;
        const int c0 = ks * 16 + kh * 8;
        _Float16* outp = &XTs[(size_t)tile * TILE_HALVES + tid * 16];
#pragma unroll
        for (int rr = 0; rr < 2; ++rr) {
            const float* s = &sb[(rp + rr) * D + c0];
            half8 hv, lv;
#pragma unroll
            for (int e = 0; e < 8; ++e) {
                float v = s[e];
                _Float16 hh = (_Float16)v;
                hv[e] = hh; lv[e] = (_Float16)(v - (float)hh);
            }
            *(half8*)&outp[rr * 8]        = hv;
            *(half8*)&outp[4096 + rr * 8] = lv;
        }
    }
    {   // norms
        const int row = tid >> 3, seg = tid & 7;
        const float4* rp4 = (const float4*)&sb[row * D];
        float q[4];
#pragma unroll
        for (int c = 0; c < 4; ++c) {
            float4 v = rp4[seg * 4 + c];
            q[c] = v.x * v.x + v.y * v.y + v.z * v.z + v.w * v.w;
        }
        float part = (q[0] + q[1]) + (q[2] + q[3]);
        part += __shfl_xor(part, 1);
        part += __shfl_xor(part, 2);
        part += __shfl_xor(part, 4);
        if (seg == 0) {
            const float m = -0.5f * part;
            const _Float16 mh = (_Float16)m;
            const _Float16 ml = (_Float16)(m - (float)mh);
            union { _Float16 h[2]; uint32_t u; } cv;
            cv.h[0] = mh; cv.h[1] = ml;
            nrmp[tile * 32 + row] = cv.u;
        }
    }
}

template <bool SPLIT>
__global__ __launch_bounds__(256, 4)
void knn_mfma(const float* __restrict__ X, const float* __restrict__ XT,
              const _Float16* __restrict__ XTs, const uint32_t* __restrict__ nrmp,
              Cand* __restrict__ part, int nch, int chunk) {
    __shared__ __align__(16) _Float16 lds[2][TILE_HALVES];   // 32 KB

    const int tid  = threadIdx.x;
    const int lane = tid & 63;
    const int wv   = tid >> 6;
    const int bx   = blockIdx.x;
    const int bc   = blockIdx.y;

    // ---- persistent B (tests) fragments, hi/lo split ----
    half8 Bh[2][8], Bl[2][8];
#pragma unroll
    for (int c = 0; c < 2; ++c) {
        const int trow = bx * TB + wv * 64 + c * 32 + (lane & 31);
        const float* xp = &X[(size_t)trow * D + (lane >> 5) * 8];
#pragma unroll
        for (int ks = 0; ks < 8; ++ks) {
            float4 v0 = *(const float4*)&xp[ks * 16];
            float4 v1 = *(const float4*)&xp[ks * 16 + 4];
            float a[8] = {v0.x, v0.y, v0.z, v0.w, v1.x, v1.y, v1.z, v1.w};
#pragma unroll
            for (int e = 0; e < 8; ++e) {
                _Float16 hh = (_Float16)a[e];
                Bh[c][ks][e] = hh;
                Bl[c][ks][e] = (_Float16)(a[e] - (float)hh);
            }
        }
    }
    half8 B8;
#pragma unroll
    for (int e = 0; e < 8; ++e) B8[e] = (_Float16)0.0f;
    if (lane < 32) B8[0] = (_Float16)1.0f;

    const int srow = tid & 31;
    const int ksp  = tid >> 5;
    float a16[16];

    auto issue_stage_split = [&](int buf, int tile) {
        const _Float16* g = &XTs[(size_t)tile * TILE_HALVES + wv * 512 + lane * 8];
        _Float16* l = &lds[buf][wv * 512];
#pragma unroll
        for (int p = 0; p < 4; ++p)
            gload_lds16(g + p * 2048, l + p * 2048);
    };
    auto issue_loads = [&](int jb) {
        int j = jb + srow;
        if (j > NTRAIN - 1) j = NTRAIN - 1;
        const float4* p = (const float4*)&XT[(size_t)j * D + ksp * 16];
        float4 v0 = p[0], v1 = p[1], v2 = p[2], v3 = p[3];
        a16[0]=v0.x; a16[1]=v0.y; a16[2]=v0.z; a16[3]=v0.w;
        a16[4]=v1.x; a16[5]=v1.y; a16[6]=v1.z; a16[7]=v1.w;
        a16[8]=v2.x; a16[9]=v2.y; a16[10]=v2.z; a16[11]=v2.w;
        a16[12]=v3.x; a16[13]=v3.y; a16[14]=v3.z; a16[15]=v3.w;
    };
    auto write_stage = [&](int buf) {
        half8 hv0, lv0, hv1, lv1;
#pragma unroll
        for (int e = 0; e < 8; ++e) {
            _Float16 hh = (_Float16)a16[e];
            hv0[e] = hh; lv0[e] = (_Float16)(a16[e] - (float)hh);
        }
#pragma unroll
        for (int e = 0; e < 8; ++e) {
            _Float16 hh = (_Float16)a16[8 + e];
            hv1[e] = hh; lv1[e] = (_Float16)(a16[8 + e] - (float)hh);
        }
        _Float16* base = &lds[buf][ksp * 512 + srow * 8];
        *(half8*)(base)              = hv0;
        *(half8*)(base + 256)        = hv1;
        *(half8*)(base + 4096)       = lv0;
        *(half8*)(base + 4096 + 256) = lv1;
    };

    Cand top[2][KNN];
#pragma unroll
    for (int c = 0; c < 2; ++c)
#pragma unroll
        for (int e = 0; e < KNN; ++e) top[c][e] = {-FLT_MAX, 0x7fffffff};

    const int jc0 = bc * chunk;
    const int ntiles = chunk >> 5;
    const int tile0 = jc0 >> 5;

    if (SPLIT) {
        issue_stage_split(0, tile0);
    } else {
        issue_loads(jc0);
        write_stage(0);
    }
    __syncthreads();

    for (int t = 0; t < ntiles; ++t) {
        const int jb = jc0 + t * NT;
        if (jb >= NTRAIN) break;                    // uniform across block
        const int buf = t & 1;
        const bool more = (t + 1 < ntiles);

        if (SPLIT) {
            if (more) issue_stage_split(buf ^ 1, tile0 + t + 1);
        } else {
            if (more) issue_loads(jb + NT);
        }

        // augment source (branch-free; all real tiles have jb+31 < NTRAIN)
        int nj = jb + (lane & 31);
        if (!SPLIT && nj > NTRAIN - 1) nj = NTRAIN - 1;
        uint32_t nv = nrmp[nj];
        if (lane >= 32) nv = 0;

        f32x16 accA, accB;
#pragma unroll
        for (int e = 0; e < 16; ++e) { accA[e] = 0.f; accB[e] = 0.f; }

        const _Float16* rbase = &lds[buf][lane * 8];
        __builtin_amdgcn_s_setprio(1);
#pragma unroll
        for (int ks = 0; ks < 8; ++ks) {
            half8 ah = *(const half8*)(rbase + ks * 512);
            half8 al = *(const half8*)(rbase + 4096 + ks * 512);
            accA = MFMA(ah, Bh[0][ks], accA);
            accB = MFMA(ah, Bh[1][ks], accB);
            accA = MFMA(ah, Bl[0][ks], accA);
            accB = MFMA(ah, Bl[1][ks], accB);
            accA = MFMA(al, Bh[0][ks], accA);
            accB = MFMA(al, Bh[1][ks], accB);
        }
        {   // augmented passes (bit-identical: +mh then +ml)
            union { uint32_t u; _Float16 h[2]; } cv; cv.u = nv;
            half8 augh, augl;
#pragma unroll
            for (int e = 0; e < 8; ++e) { augh[e] = (_Float16)0.0f; augl[e] = (_Float16)0.0f; }
            augh[0] = cv.h[0];
            augl[0] = cv.h[1];
            accA = MFMA(augh, B8, accA);
            accB = MFMA(augh, B8, accB);
            accA = MFMA(augl, B8, accA);
            accB = MFMA(augl, B8, accB);
        }
        __builtin_amdgcn_s_setprio(0);

        if (!SPLIT && more) write_stage(buf ^ 1);

        // ---- epilogue: acc-level prefilter + per-reg guards ----
        // Per-lane j stream is ascending, so strict '>' guard preserves the
        // tie->smaller-index semantics exactly.
        const int rb = 4 * (lane >> 5);
        if (max16(accA) > top[0][4].s) {
#pragma unroll
            for (int reg = 0; reg < 16; ++reg) {
                const float s = accA[reg];
                if (s > top[0][4].s) {
                    const int j = jb + (reg & 3) + 8 * (reg >> 2) + rb;
                    if (SPLIT || j < NTRAIN) ins5(top[0], s, j);
                }
            }
        }
        if (max16(accB) > top[1][4].s) {
#pragma unroll
            for (int reg = 0; reg < 16; ++reg) {
                const float s = accB[reg];
                if (s > top[1][4].s) {
                    const int j = jb + (reg & 3) + 8 * (reg >> 2) + rb;
                    if (SPLIT || j < NTRAIN) ins5(top[1], s, j);
                }
            }
        }
        __syncthreads();
    }

    // ---- merge lane pairs (l <-> l+32), write partials (all blocks write) ----
#pragma unroll
    for (int c = 0; c < 2; ++c) {
        float os[KNN]; int oj[KNN];
#pragma unroll
        for (int e = 0; e < KNN; ++e) {
            os[e] = __shfl_xor(top[c][e].s, 32);
            oj[e] = __shfl_xor(top[c][e].j, 32);
        }
#pragma unroll
        for (int e = 0; e < KNN; ++e) ins5(top[c], os[e], oj[e]);
        if (lane < 32) {
            const int test = bx * TB + wv * 64 + c * 32 + lane;
            Cand* pp = &part[((size_t)test * nch + bc) * KNN];
#pragma unroll
            for (int e = 0; e < KNN; ++e) pp[e] = top[c][e];
        }
    }
}

// ---- parallel vote: one wave per test; lanes split chunks, butterfly merge ----
__global__ __launch_bounds__(256)
void knn_vote2(const Cand* __restrict__ part, const int* __restrict__ y,
               float* __restrict__ out, int nch) {
    const int tid  = threadIdx.x;
    const int lane = tid & 63;
    const int test = blockIdx.x * 4 + (tid >> 6);
    if (test >= T) return;

    Cand best[KNN];
#pragma unroll
    for (int e = 0; e < KNN; ++e) best[e] = {-FLT_MAX, 0x7fffffff};

    for (int c = lane; c < nch; c += 64) {
        const Cand* pp = &part[((size_t)test * nch + c) * KNN];
#pragma unroll
        for (int e = 0; e < KNN; ++e) {
            const Cand cc = pp[e];
            if ((unsigned)cc.j < (unsigned)NTRAIN) ins5(best, cc.s, cc.j);
        }
    }
#pragma unroll
    for (int off = 32; off >= 1; off >>= 1) {
        float os[KNN]; int oj[KNN];
#pragma unroll
        for (int e = 0; e < KNN; ++e) {
            os[e] = __shfl_xor(best[e].s, off);
            oj[e] = __shfl_xor(best[e].j, off);
        }
#pragma unroll
        for (int e = 0; e < KNN; ++e)
            if ((unsigned)oj[e] < (unsigned)NTRAIN) ins5(best, os[e], oj[e]);
    }
    if (lane == 0) {
        int lbl[KNN];
#pragma unroll
        for (int e = 0; e < KNN; ++e) lbl[e] = y[best[e].j];
        int bestc = 0, bestcnt = -1;
#pragma unroll
        for (int c = 0; c < NUM_CLASSES; ++c) {
            int cnt = 0;
#pragma unroll
            for (int e = 0; e < KNN; ++e) cnt += (lbl[e] == c) ? 1 : 0;
            if (cnt > bestcnt) { bestcnt = cnt; bestc = c; }
        }
        out[test] = (float)bestc;
    }
}

extern "C" void kernel_launch(void* const* d_in, const int* in_sizes, int n_in,
                              void* d_out, int out_size, void* d_ws, size_t ws_size,
                              hipStream_t stream) {
    const float* X  = (const float*)d_in[0];
    const float* XT = (const float*)d_in[1];
    const int*   y  = (const int*)d_in[2];
    // d_in[3] = k (always 5; hardcoded)

    const size_t xts_bytes = (size_t)NTILE_TOT * TILE_HALVES * 2;       // 51.2 MB
    const size_t nrm_bytes = ((size_t)NTRAIN * 4 + 255) & ~(size_t)255; // 400128
    const size_t per_chunk = (size_t)T * KNN * sizeof(Cand);            // 40960 B

    const size_t base = xts_bytes + nrm_bytes;

    int nch = 0;
    if (ws_size >= base + 256 * per_chunk)      nch = 256;  // 1024 blocks, 4/CU
    else if (ws_size >= base + 125 * per_chunk) nch = 125;  // r4 config

    if (nch > 0) {
        _Float16* XTs  = (_Float16*)d_ws;
        uint32_t* nrmp = (uint32_t*)((char*)d_ws + xts_bytes);
        Cand*     part = (Cand*)((char*)d_ws + base);
        const int chunk = (((NTRAIN + nch - 1) / nch) + (NT - 1)) & ~(NT - 1);
        knn_pack<<<NTILE_TOT, 256, 0, stream>>>(XT, XTs, nrmp);
        knn_mfma<true><<<dim3(T / TB, nch), 256, 0, stream>>>(X, XT, XTs, nrmp, part, nch, chunk);
        knn_vote2<<<T / 4, 256, 0, stream>>>(part, y, (float*)d_out, nch);
    } else {
        // fallback: in-loop conversion, smaller ws footprint
        uint32_t* nrmp = (uint32_t*)d_ws;
        Cand*     part = (Cand*)((char*)d_ws + nrm_bytes);
        int fch = 125;
        if (nrm_bytes + (size_t)fch * per_chunk > ws_size) {
            size_t avail = (ws_size > nrm_bytes) ? (ws_size - nrm_bytes) : 0;
            fch = (int)(avail / per_chunk);
            if (fch < 1) fch = 1;
        }
        const int chunk = (((NTRAIN + fch - 1) / fch) + (NT - 1)) & ~(NT - 1);
        knn_norms<<<(NTRAIN + 255) / 256, 256, 0, stream>>>(XT, nrmp);
        knn_mfma<false><<<dim3(T / TB, fch), 256, 0, stream>>>(X, XT, nullptr, nrmp, part, fch, chunk);
        knn_vote2<<<T / 4, 256, 0, stream>>>(part, y, (float*)d_out, fch);
    }
}

// Round 6
// 177.912 us; speedup vs baseline: 1.5409x; 1.5409x over previous
//
#include <hip/hip_runtime.h>
#include <cfloat>
#include <cstdint>

// KNN classify via split-f16 MFMA emulated-fp32 GEMM.
// key = dot(x,t) - ||t||^2/2 ; dot = hiA*hiB + hiA*loB + loA*hiB (f32-accum MFMA).
// X_train pre-split into tile-packed f16 hi/lo; staged via global_load_lds.
// Norm folded via 2 augment MFMAs (per-acc chain bit-identical to r3/r4/r5).
// Top-5 largest keys, ties -> smaller train index (lax.top_k on -dist semantics).
// r6: TB=128 (1 colfrag/wave) to halve register state (r5 spilled at 64 VGPR:
// WRITE_SIZE 101MB vs 10.5MB of real output), nch=125 grid=1000, quad prefilter.

#define NTRAIN 100000
#define D 128
#define T 1024
#define TB 128          // tests per block (4 waves x 32)
#define NT 32           // trains per tile
#define KNN 5
#define NUM_CLASSES 10
#define NCH 125         // 125 chunks x 800 trains = 100000 exactly
#define NTILE_TOT 3125  // NTRAIN / NT exactly
#define TILE_HALVES 8192   // per packed tile: hi 4096 + lo 4096 halves (16KB)

typedef _Float16 half8 __attribute__((ext_vector_type(8)));
typedef float f32x16 __attribute__((ext_vector_type(16)));

#define MFMA(a, b, c) __builtin_amdgcn_mfma_f32_32x32x16_f16((a), (b), (c), 0, 0, 0)

struct Cand { float s; int j; };

__device__ __forceinline__ bool better(float s, int j, const Cand& c) {
    return (s > c.s) || (s == c.s && j < c.j);
}

__device__ __forceinline__ void ins5(Cand t5[KNN], float s, int j) {
    if (!better(s, j, t5[4])) return;
    if (better(s, j, t5[0]))      { t5[4]=t5[3]; t5[3]=t5[2]; t5[2]=t5[1]; t5[1]=t5[0]; t5[0]={s,j}; }
    else if (better(s, j, t5[1])) { t5[4]=t5[3]; t5[3]=t5[2]; t5[2]=t5[1]; t5[1]={s,j}; }
    else if (better(s, j, t5[2])) { t5[4]=t5[3]; t5[3]=t5[2]; t5[2]={s,j}; }
    else if (better(s, j, t5[3])) { t5[4]=t5[3]; t5[3]={s,j}; }
    else                          { t5[4]={s,j}; }
}

__device__ __forceinline__ void gload_lds16(const void* g, void* l) {
    __builtin_amdgcn_global_load_lds(
        (const __attribute__((address_space(1))) uint32_t*)g,
        (__attribute__((address_space(3))) uint32_t*)l, 16, 0, 0);
}

// ---- norms only (fallback path) — tree bit-matches r2..r5 validated kernels ----
__global__ __launch_bounds__(256)
void knn_norms(const float* __restrict__ XT, uint32_t* __restrict__ nrmp) {
    const int j = blockIdx.x * 256 + threadIdx.x;
    if (j >= NTRAIN) return;
    const float4* row = (const float4*)&XT[(size_t)j * D];
    float p[32];
#pragma unroll
    for (int c = 0; c < 32; ++c) {
        float4 v = row[c];
        p[c] = v.x * v.x + v.y * v.y + v.z * v.z + v.w * v.w;
    }
#pragma unroll
    for (int s = 1; s < 32; s <<= 1)
#pragma unroll
        for (int i = 0; i < 32; i += 2 * s) p[i] += p[i + s];
    const float m = -0.5f * p[0];
    const _Float16 mh = (_Float16)m;
    const _Float16 ml = (_Float16)(m - (float)mh);
    union { _Float16 h[2]; uint32_t u; } cv;
    cv.h[0] = mh; cv.h[1] = ml;
    nrmp[j] = cv.u;
}

// ---- fused: pack XT into tile-packed hi/lo f16 + packed norms (validated r5) ----
__global__ __launch_bounds__(256)
void knn_pack(const float* __restrict__ XT, _Float16* __restrict__ XTs,
              uint32_t* __restrict__ nrmp) {
    __shared__ __align__(16) float sb[32 * D];
    const int tid  = threadIdx.x;
    const int tile = blockIdx.x;
    const float4* src = (const float4*)&XT[(size_t)tile * 32 * D];
#pragma unroll
    for (int p = 0; p < 4; ++p)
        *(float4*)&sb[(p * 256 + tid) * 4] = src[p * 256 + tid];
    __syncthreads();

    {   // pack
        const int ks = tid >> 5, kh = (tid >> 4) & 1, rp = (tid & 15) * 2;
        const int c0 = ks * 16 + kh * 8;
        _Float16* outp = &XTs[(size_t)tile * TILE_HALVES + tid * 16];
#pragma unroll
        for (int rr = 0; rr < 2; ++rr) {
            const float* s = &sb[(rp + rr) * D + c0];
            half8 hv, lv;
#pragma unroll
            for (int e = 0; e < 8; ++e) {
                float v = s[e];
                _Float16 hh = (_Float16)v;
                hv[e] = hh; lv[e] = (_Float16)(v - (float)hh);
            }
            *(half8*)&outp[rr * 8]        = hv;
            *(half8*)&outp[4096 + rr * 8] = lv;
        }
    }
    {   // norms (pairing tree identical to knn_norms)
        const int row = tid >> 3, seg = tid & 7;
        const float4* rp4 = (const float4*)&sb[row * D];
        float q[4];
#pragma unroll
        for (int c = 0; c < 4; ++c) {
            float4 v = rp4[seg * 4 + c];
            q[c] = v.x * v.x + v.y * v.y + v.z * v.z + v.w * v.w;
        }
        float part = (q[0] + q[1]) + (q[2] + q[3]);
        part += __shfl_xor(part, 1);
        part += __shfl_xor(part, 2);
        part += __shfl_xor(part, 4);
        if (seg == 0) {
            const float m = -0.5f * part;
            const _Float16 mh = (_Float16)m;
            const _Float16 ml = (_Float16)(m - (float)mh);
            union { _Float16 h[2]; uint32_t u; } cv;
            cv.h[0] = mh; cv.h[1] = ml;
            nrmp[tile * 32 + row] = cv.u;
        }
    }
}

template <bool SPLIT>
__global__ __launch_bounds__(256, 3)
void knn_mfma(const float* __restrict__ X, const float* __restrict__ XT,
              const _Float16* __restrict__ XTs, const uint32_t* __restrict__ nrmp,
              Cand* __restrict__ part, int nch, int chunk) {
    __shared__ __align__(16) _Float16 lds[2][TILE_HALVES];   // 32 KB

    const int tid  = threadIdx.x;
    const int lane = tid & 63;
    const int wv   = tid >> 6;
    const int bx   = blockIdx.x;   // 0..7 (test group of 128)
    const int bc   = blockIdx.y;   // chunk

    // ---- persistent B (tests) fragment: ONE colfrag per wave (32 tests) ----
    half8 Bh[8], Bl[8];
    {
        const int trow = bx * TB + wv * 32 + (lane & 31);
        const float* xp = &X[(size_t)trow * D + (lane >> 5) * 8];
#pragma unroll
        for (int ks = 0; ks < 8; ++ks) {
            float4 v0 = *(const float4*)&xp[ks * 16];
            float4 v1 = *(const float4*)&xp[ks * 16 + 4];
            float a[8] = {v0.x, v0.y, v0.z, v0.w, v1.x, v1.y, v1.z, v1.w};
#pragma unroll
            for (int e = 0; e < 8; ++e) {
                _Float16 hh = (_Float16)a[e];
                Bh[ks][e] = hh;
                Bl[ks][e] = (_Float16)(a[e] - (float)hh);
            }
        }
    }
    half8 B8;
#pragma unroll
    for (int e = 0; e < 8; ++e) B8[e] = (_Float16)0.0f;
    if (lane < 32) B8[0] = (_Float16)1.0f;

    const int srow = tid & 31;
    const int ksp  = tid >> 5;
    float a16[16];

    auto issue_stage_split = [&](int buf, int tile) {
        const _Float16* g = &XTs[(size_t)tile * TILE_HALVES + wv * 512 + lane * 8];
        _Float16* l = &lds[buf][wv * 512];
#pragma unroll
        for (int p = 0; p < 4; ++p)
            gload_lds16(g + p * 2048, l + p * 2048);
    };
    auto issue_loads = [&](int jb) {
        int j = jb + srow;
        if (j > NTRAIN - 1) j = NTRAIN - 1;
        const float4* p = (const float4*)&XT[(size_t)j * D + ksp * 16];
        float4 v0 = p[0], v1 = p[1], v2 = p[2], v3 = p[3];
        a16[0]=v0.x; a16[1]=v0.y; a16[2]=v0.z; a16[3]=v0.w;
        a16[4]=v1.x; a16[5]=v1.y; a16[6]=v1.z; a16[7]=v1.w;
        a16[8]=v2.x; a16[9]=v2.y; a16[10]=v2.z; a16[11]=v2.w;
        a16[12]=v3.x; a16[13]=v3.y; a16[14]=v3.z; a16[15]=v3.w;
    };
    auto write_stage = [&](int buf) {
        half8 hv0, lv0, hv1, lv1;
#pragma unroll
        for (int e = 0; e < 8; ++e) {
            _Float16 hh = (_Float16)a16[e];
            hv0[e] = hh; lv0[e] = (_Float16)(a16[e] - (float)hh);
        }
#pragma unroll
        for (int e = 0; e < 8; ++e) {
            _Float16 hh = (_Float16)a16[8 + e];
            hv1[e] = hh; lv1[e] = (_Float16)(a16[8 + e] - (float)hh);
        }
        _Float16* base = &lds[buf][ksp * 512 + srow * 8];
        *(half8*)(base)              = hv0;
        *(half8*)(base + 256)        = hv1;
        *(half8*)(base + 4096)       = lv0;
        *(half8*)(base + 4096 + 256) = lv1;
    };

    Cand top5[KNN];
#pragma unroll
    for (int e = 0; e < KNN; ++e) top5[e] = {-FLT_MAX, 0x7fffffff};

    const int jc0 = bc * chunk;
    const int ntiles = chunk >> 5;
    const int tile0 = jc0 >> 5;

    if (SPLIT) {
        issue_stage_split(0, tile0);
    } else {
        issue_loads(jc0);
        write_stage(0);
    }
    __syncthreads();

    for (int t = 0; t < ntiles; ++t) {
        const int jb = jc0 + t * NT;
        if (!SPLIT && jb >= NTRAIN) break;          // fallback only (uniform)
        const int buf = t & 1;
        const bool more = (t + 1 < ntiles);

        if (SPLIT) {
            if (more) issue_stage_split(buf ^ 1, tile0 + t + 1);
        } else {
            if (more) issue_loads(jb + NT);
        }

        // augment source (lanes 0..31 carry rows)
        int nj = jb + (lane & 31);
        if (!SPLIT && nj > NTRAIN - 1) nj = NTRAIN - 1;
        uint32_t nv = nrmp[nj];
        if (lane >= 32) nv = 0;

        f32x16 acc;
#pragma unroll
        for (int e = 0; e < 16; ++e) acc[e] = 0.f;

        const _Float16* rbase = &lds[buf][lane * 8];
        __builtin_amdgcn_s_setprio(1);
#pragma unroll
        for (int ks = 0; ks < 8; ++ks) {
            half8 ah = *(const half8*)(rbase + ks * 512);
            half8 al = *(const half8*)(rbase + 4096 + ks * 512);
            acc = MFMA(ah, Bh[ks], acc);
            acc = MFMA(ah, Bl[ks], acc);
            acc = MFMA(al, Bh[ks], acc);
        }
        {   // augmented passes (+mh then +ml) — same chain as validated rounds
            union { uint32_t u; _Float16 h[2]; } cv; cv.u = nv;
            half8 augh, augl;
#pragma unroll
            for (int e = 0; e < 8; ++e) { augh[e] = (_Float16)0.0f; augl[e] = (_Float16)0.0f; }
            augh[0] = cv.h[0];
            augl[0] = cv.h[1];
            acc = MFMA(augh, B8, acc);
            acc = MFMA(augl, B8, acc);
        }
        __builtin_amdgcn_s_setprio(0);

        if (!SPLIT && more) write_stage(buf ^ 1);

        // ---- epilogue: quad prefilter, descend only into hot quads ----
        // Per-lane j stream ascending => strict '>' keeps smaller index on ties.
        const int rb = 4 * (lane >> 5);
        float qm[4];
#pragma unroll
        for (int qq = 0; qq < 4; ++qq)
            qm[qq] = fmaxf(fmaxf(acc[qq * 4], acc[qq * 4 + 1]),
                           fmaxf(acc[qq * 4 + 2], acc[qq * 4 + 3]));
        const float M = fmaxf(fmaxf(qm[0], qm[1]), fmaxf(qm[2], qm[3]));
        if (M > top5[4].s) {
#pragma unroll
            for (int qq = 0; qq < 4; ++qq) {
                if (qm[qq] > top5[4].s) {
#pragma unroll
                    for (int r = 0; r < 4; ++r) {
                        const int reg = qq * 4 + r;
                        const float s = acc[reg];
                        if (s > top5[4].s) {
                            const int j = jb + (reg & 3) + 8 * (reg >> 2) + rb;
                            if (SPLIT || j < NTRAIN) ins5(top5, s, j);
                        }
                    }
                }
            }
        }
        __syncthreads();
    }

    // ---- merge lane pairs (l <-> l+32), write partials ----
    {
        float os[KNN]; int oj[KNN];
#pragma unroll
        for (int e = 0; e < KNN; ++e) {
            os[e] = __shfl_xor(top5[e].s, 32);
            oj[e] = __shfl_xor(top5[e].j, 32);
        }
#pragma unroll
        for (int e = 0; e < KNN; ++e) ins5(top5, os[e], oj[e]);
        if (lane < 32) {
            const int test = bx * TB + wv * 32 + lane;
            Cand* pp = &part[((size_t)test * nch + bc) * KNN];
#pragma unroll
            for (int e = 0; e < KNN; ++e) pp[e] = top5[e];
        }
    }
}

// ---- parallel vote: one wave per test; lanes split chunks, butterfly merge ----
__global__ __launch_bounds__(256)
void knn_vote2(const Cand* __restrict__ part, const int* __restrict__ y,
               float* __restrict__ out, int nch) {
    const int tid  = threadIdx.x;
    const int lane = tid & 63;
    const int test = blockIdx.x * 4 + (tid >> 6);
    if (test >= T) return;

    Cand best[KNN];
#pragma unroll
    for (int e = 0; e < KNN; ++e) best[e] = {-FLT_MAX, 0x7fffffff};

    for (int c = lane; c < nch; c += 64) {
        const Cand* pp = &part[((size_t)test * nch + c) * KNN];
#pragma unroll
        for (int e = 0; e < KNN; ++e) {
            const Cand cc = pp[e];
            if ((unsigned)cc.j < (unsigned)NTRAIN) ins5(best, cc.s, cc.j);
        }
    }
#pragma unroll
    for (int off = 32; off >= 1; off >>= 1) {
        float os[KNN]; int oj[KNN];
#pragma unroll
        for (int e = 0; e < KNN; ++e) {
            os[e] = __shfl_xor(best[e].s, off);
            oj[e] = __shfl_xor(best[e].j, off);
        }
#pragma unroll
        for (int e = 0; e < KNN; ++e)
            if ((unsigned)oj[e] < (unsigned)NTRAIN) ins5(best, os[e], oj[e]);
    }
    if (lane == 0) {
        int lbl[KNN];
#pragma unroll
        for (int e = 0; e < KNN; ++e) lbl[e] = y[best[e].j];
        int bestc = 0, bestcnt = -1;
#pragma unroll
        for (int c = 0; c < NUM_CLASSES; ++c) {
            int cnt = 0;
#pragma unroll
            for (int e = 0; e < KNN; ++e) cnt += (lbl[e] == c) ? 1 : 0;
            if (cnt > bestcnt) { bestcnt = cnt; bestc = c; }
        }
        out[test] = (float)bestc;
    }
}

extern "C" void kernel_launch(void* const* d_in, const int* in_sizes, int n_in,
                              void* d_out, int out_size, void* d_ws, size_t ws_size,
                              hipStream_t stream) {
    const float* X  = (const float*)d_in[0];
    const float* XT = (const float*)d_in[1];
    const int*   y  = (const int*)d_in[2];
    // d_in[3] = k (always 5; hardcoded)

    const size_t xts_bytes = (size_t)NTILE_TOT * TILE_HALVES * 2;       // 51.2 MB
    const size_t nrm_bytes = ((size_t)NTRAIN * 4 + 255) & ~(size_t)255; // 400128
    const size_t per_chunk = (size_t)T * KNN * sizeof(Cand);            // 40960 B
    const size_t base = xts_bytes + nrm_bytes;

    if (ws_size >= base + NCH * per_chunk) {
        _Float16* XTs  = (_Float16*)d_ws;
        uint32_t* nrmp = (uint32_t*)((char*)d_ws + xts_bytes);
        Cand*     part = (Cand*)((char*)d_ws + base);
        const int chunk = NTRAIN / NCH;   // 800, exact
        knn_pack<<<NTILE_TOT, 256, 0, stream>>>(XT, XTs, nrmp);
        knn_mfma<true><<<dim3(T / TB, NCH), 256, 0, stream>>>(X, XT, XTs, nrmp, part, NCH, chunk);
        knn_vote2<<<T / 4, 256, 0, stream>>>(part, y, (float*)d_out, NCH);
    } else {
        // fallback: in-loop conversion, smaller ws footprint
        uint32_t* nrmp = (uint32_t*)d_ws;
        Cand*     part = (Cand*)((char*)d_ws + nrm_bytes);
        int fch = NCH;
        if (nrm_bytes + (size_t)fch * per_chunk > ws_size) {
            size_t avail = (ws_size > nrm_bytes) ? (ws_size - nrm_bytes) : 0;
            fch = (int)(avail / per_chunk);
            if (fch < 1) fch = 1;
        }
        const int chunk = (((NTRAIN + fch - 1) / fch) + (NT - 1)) & ~(NT - 1);
        knn_norms<<<(NTRAIN + 255) / 256, 256, 0, stream>>>(XT, nrmp);
        knn_mfma<false><<<dim3(T / TB, fch), 256, 0, stream>>>(X, XT, nullptr, nrmp, part, fch, chunk);
        knn_vote2<<<T / 4, 256, 0, stream>>>(part, y, (float*)d_out, fch);
    }
}